// Round 7
// baseline (128.122 us; speedup 1.0000x reference)
//
#include <hip/hip_runtime.h>

#define VR 4
#define NVOX 64            // VR^3
#define NCLS 40
#define NB 64
#define NPTS 100000
#define BPB 16             // blocks per batch
#define NBLK (NB * BPB)
#define G_PER_B (NPTS / 4)        // 25000 groups of 4 points (= 3 float4 each)
#define F4_PER_B (NPTS * 3 / 4)   // 75000 float4 per batch
#define STRIDE_G (BPB * 256)      // 4096 groups per step
#define FULL_ITERS (G_PER_B / STRIDE_G)            // 6 full (all-valid) iters
#define NT_ITERS 4                // k<4: nontemporal (keep out of L2)
#define TAIL_G (G_PER_B - FULL_ITERS * STRIDE_G)   // 424 ragged groups
#define SW_LD 41                  // padded leading dim for transposed W in LDS
#define FLT_BIG 3.402823466e38f

typedef float f4 __attribute__((ext_vector_type(4)));

static __device__ __forceinline__ int bin1(float v, float mn, float s4) {
    int i = (int)((v - mn) * s4);   // v>=mn, s4>0 -> trunc==floor
    return i > (VR - 1) ? (VR - 1) : i;
}

// lane L of the wave owns voxel L: AND of per-bit (ballot XOR lane-complement)
static __device__ __forceinline__ unsigned long long vox_mask(
        int v, const unsigned long long* ns) {
    return (__ballot(v & 1)  ^ ns[0]) & (__ballot(v & 2)  ^ ns[1])
         & (__ballot(v & 4)  ^ ns[2]) & (__ballot(v & 8)  ^ ns[3])
         & (__ballot(v & 16) ^ ns[4]) & (__ballot(v & 32) ^ ns[5]);
}

// ---------------------------------------------------------------------------
// Block labeling (BOTH kernels): b = bid & 63, sub = bid >> 6. With
// round-robin bid->XCD (bid % 8), all 16 blocks of batch b sit on XCD b%8 in
// BOTH launches -> k2 re-reads k1's lines from the same L2. Heuristic only.
// ---------------------------------------------------------------------------

// ---------------------------------------------------------------------------
// Kernel 1: per-block per-dim min/max partials (pure ~77 MB HBM stream).
// Iterations k<4 load NONTEMPORAL so only the k=4,5+tail portion (~3.4 MB
// per XCD < 4 MB L2) stays L2-resident for kernel 2's first reads.
// sub==0 blocks also zero out[b] (ordered before k2 by the kernel boundary).
// ---------------------------------------------------------------------------
__global__ __launch_bounds__(256) void minmax_k(const f4* __restrict__ x,
                                                float* __restrict__ pmin,
                                                float* __restrict__ pmax,
                                                float* __restrict__ out) {
    const int bid = blockIdx.x;
    const int b = bid & (NB - 1);
    const int sub = bid >> 6;
    const f4* xb = x + (size_t)b * F4_PER_B;
    const int lane = threadIdx.x & 63;
    const int wv = threadIdx.x >> 6;
    const int t0 = sub * 256 + (int)threadIdx.x;

    if (sub == 0 && threadIdx.x < NCLS)   // zero the atomic accumulator
        out[b * NCLS + threadIdx.x] = 0.f;

    float mn0 = FLT_BIG, mn1 = FLT_BIG, mn2 = FLT_BIG;
    float mx0 = -FLT_BIG, mx1 = -FLT_BIG, mx2 = -FLT_BIG;
    #pragma unroll
    for (int k = 0; k < FULL_ITERS; k++) {         // no predication in hot loop
        const int g = t0 + k * STRIDE_G;
        f4 a, c, e;
        if (k < NT_ITERS) {                        // folded per unrolled k
            a = __builtin_nontemporal_load(&xb[3 * g]);
            c = __builtin_nontemporal_load(&xb[3 * g + 1]);
            e = __builtin_nontemporal_load(&xb[3 * g + 2]);
        } else {                                   // cached: k2 reads these 1st
            a = xb[3 * g]; c = xb[3 * g + 1]; e = xb[3 * g + 2];
        }
        // flat%3: a0->0 a1->1 a2->2 a3->0 c0->1 c1->2 c2->0 c3->1
        //         e0->2 e1->0 e2->1 e3->2
        mn0 = fminf(mn0, fminf(fminf(a[0], a[3]), fminf(c[2], e[1])));
        mx0 = fmaxf(mx0, fmaxf(fmaxf(a[0], a[3]), fmaxf(c[2], e[1])));
        mn1 = fminf(mn1, fminf(fminf(a[1], c[0]), fminf(c[3], e[2])));
        mx1 = fmaxf(mx1, fmaxf(fmaxf(a[1], c[0]), fmaxf(c[3], e[2])));
        mn2 = fminf(mn2, fminf(fminf(a[2], c[1]), fminf(e[0], e[3])));
        mx2 = fmaxf(mx2, fmaxf(fmaxf(a[2], c[1]), fmaxf(e[0], e[3])));
    }
    if (sub * 256 < TAIL_G && t0 < TAIL_G) {       // ragged tail: subs 0,1 only
        const int g = FULL_ITERS * STRIDE_G + t0;
        const f4 a = xb[3 * g], c = xb[3 * g + 1], e = xb[3 * g + 2];
        mn0 = fminf(mn0, fminf(fminf(a[0], a[3]), fminf(c[2], e[1])));
        mx0 = fmaxf(mx0, fmaxf(fmaxf(a[0], a[3]), fmaxf(c[2], e[1])));
        mn1 = fminf(mn1, fminf(fminf(a[1], c[0]), fminf(c[3], e[2])));
        mx1 = fmaxf(mx1, fmaxf(fmaxf(a[1], c[0]), fmaxf(c[3], e[2])));
        mn2 = fminf(mn2, fminf(fminf(a[2], c[1]), fminf(e[0], e[3])));
        mx2 = fmaxf(mx2, fmaxf(fmaxf(a[2], c[1]), fmaxf(e[0], e[3])));
    }

    #pragma unroll
    for (int off = 32; off > 0; off >>= 1) {
        mn0 = fminf(mn0, __shfl_down(mn0, off, 64));
        mn1 = fminf(mn1, __shfl_down(mn1, off, 64));
        mn2 = fminf(mn2, __shfl_down(mn2, off, 64));
        mx0 = fmaxf(mx0, __shfl_down(mx0, off, 64));
        mx1 = fmaxf(mx1, __shfl_down(mx1, off, 64));
        mx2 = fmaxf(mx2, __shfl_down(mx2, off, 64));
    }

    __shared__ float smn[4][3], smx[4][3];
    if (lane == 0) {
        smn[wv][0] = mn0; smn[wv][1] = mn1; smn[wv][2] = mn2;
        smx[wv][0] = mx0; smx[wv][1] = mx1; smx[wv][2] = mx2;
    }
    __syncthreads();
    if (threadIdx.x < 3) {
        const int d = threadIdx.x;
        float a = smn[0][d], z = smx[0][d];
        #pragma unroll
        for (int w = 1; w < 4; w++) {
            a = fminf(a, smn[w][d]);
            z = fmaxf(z, smx[w][d]);
        }
        pmin[(b * BPB + sub) * 3 + d] = a;
        pmax[(b * BPB + sub) * 3 + d] = z;
    }
}

// ---------------------------------------------------------------------------
// Kernel 2: issue ALL x loads into registers up-front (recency order: the
// k=5,4 portions are L2-hits from k1), overlap the sW staging and the
// pmin/pmax reduce under the load latency, then ballot-tally from registers.
// Fused partial GEMV via device atomicAdd (coherent; proven in rounds 3/5/6).
// ---------------------------------------------------------------------------
__global__ __launch_bounds__(256, 4) void hist_gemv_k(const f4* __restrict__ x,
                                                      const float* __restrict__ pmin,
                                                      const float* __restrict__ pmax,
                                                      const float* __restrict__ W,
                                                      const float* __restrict__ bias,
                                                      float* __restrict__ out) {
    const int bid = blockIdx.x;
    const int b = bid & (NB - 1);
    const int sub = bid >> 6;
    const f4* xb = x + (size_t)b * F4_PER_B;
    const int lane = threadIdx.x & 63;
    const int wv = threadIdx.x >> 6;
    const int t0 = sub * 256 + (int)threadIdx.x;

    __shared__ float sW[NVOX * SW_LD];  // transposed [f][c], padded stride 41
    __shared__ float smm[6];            // mn0 mn1 mn2 mx0 mx1 mx2
    __shared__ unsigned swh[4][NVOX];
    __shared__ float fh[NVOX];

    // ---- issue all x loads first (recency order -> L2 hits issue first) ----
    f4 A[FULL_ITERS], C[FULL_ITERS], E[FULL_ITERS];   // 72 VGPRs
    #pragma unroll
    for (int k = FULL_ITERS - 1; k >= 0; k--) {
        const int g = t0 + k * STRIDE_G;
        A[k] = xb[3 * g]; C[k] = xb[3 * g + 1]; E[k] = xb[3 * g + 2];
    }

    // ---- these overlap the x-load latency ----
    for (int i = threadIdx.x; i < NCLS * NVOX; i += 256)
        sW[(i % NVOX) * SW_LD + (i / NVOX)] = W[i];
    if (threadIdx.x < 6) {              // reduce the 16 min/max partials
        const int d = threadIdx.x % 3;
        const bool isMax = threadIdx.x >= 3;
        float r = isMax ? -FLT_BIG : FLT_BIG;
        for (int s = 0; s < BPB; s++) {
            float v = isMax ? pmax[(b * BPB + s) * 3 + d]
                            : pmin[(b * BPB + s) * 3 + d];
            r = isMax ? fmaxf(r, v) : fminf(r, v);
        }
        smm[threadIdx.x] = r;
    }
    __syncthreads();
    const float bn0 = smm[0], bn1 = smm[1], bn2 = smm[2];
    const float s40 = (float)VR / (smm[3] - smm[0]);
    const float s41 = (float)VR / (smm[4] - smm[1]);
    const float s42 = (float)VR / (smm[5] - smm[2]);

    unsigned long long ns[6];
    #pragma unroll
    for (int k = 0; k < 6; k++)
        ns[k] = ((lane >> k) & 1) ? 0ull : ~0ull;

    unsigned cnt = 0;
    if (sub * 256 < TAIL_G) {           // tail inline first (k1 read it last)
        const bool valid = t0 < TAIL_G;
        const unsigned long long vm = __ballot(valid);
        const int g = FULL_ITERS * STRIDE_G + (valid ? t0 : 0);
        const f4 a = xb[3 * g], c = xb[3 * g + 1], e = xb[3 * g + 2];
        int v0 = bin1(a[0], bn0, s40) * 16 + bin1(a[1], bn1, s41) * 4 + bin1(a[2], bn2, s42);
        int v1 = bin1(a[3], bn0, s40) * 16 + bin1(c[0], bn1, s41) * 4 + bin1(c[1], bn2, s42);
        int v2 = bin1(c[2], bn0, s40) * 16 + bin1(c[3], bn1, s41) * 4 + bin1(e[0], bn2, s42);
        int v3 = bin1(e[1], bn0, s40) * 16 + bin1(e[2], bn1, s41) * 4 + bin1(e[3], bn2, s42);
        cnt += (unsigned)__popcll(vm & vox_mask(v0, ns));
        cnt += (unsigned)__popcll(vm & vox_mask(v1, ns));
        cnt += (unsigned)__popcll(vm & vox_mask(v2, ns));
        cnt += (unsigned)__popcll(vm & vox_mask(v3, ns));
    }
    #pragma unroll
    for (int k = FULL_ITERS - 1; k >= 0; k--) {    // pure register tally
        const f4 a = A[k], c = C[k], e = E[k];
        int v0 = bin1(a[0], bn0, s40) * 16 + bin1(a[1], bn1, s41) * 4 + bin1(a[2], bn2, s42);
        int v1 = bin1(a[3], bn0, s40) * 16 + bin1(c[0], bn1, s41) * 4 + bin1(c[1], bn2, s42);
        int v2 = bin1(c[2], bn0, s40) * 16 + bin1(c[3], bn1, s41) * 4 + bin1(e[0], bn2, s42);
        int v3 = bin1(e[1], bn0, s40) * 16 + bin1(e[2], bn1, s41) * 4 + bin1(e[3], bn2, s42);
        cnt += (unsigned)__popcll(vox_mask(v0, ns));
        cnt += (unsigned)__popcll(vox_mask(v1, ns));
        cnt += (unsigned)__popcll(vox_mask(v2, ns));
        cnt += (unsigned)__popcll(vox_mask(v3, ns));
    }

    swh[wv][lane] = cnt;
    __syncthreads();
    if (threadIdx.x < NVOX)
        fh[threadIdx.x] = (float)(swh[0][threadIdx.x] + swh[1][threadIdx.x] +
                                  swh[2][threadIdx.x] + swh[3][threadIdx.x])
                          * (1.0f / (float)NPTS);
    __syncthreads();
    if (threadIdx.x < NCLS) {                      // partial GEMV + atomic sum
        const int c = threadIdx.x;
        float acc = (sub == 0) ? bias[c] : 0.f;
        #pragma unroll
        for (int f = 0; f < NVOX; f++)
            acc += fh[f] * sW[f * SW_LD + c];      // padded: conflict-free
        atomicAdd(&out[b * NCLS + c], acc);
    }
}

extern "C" void kernel_launch(void* const* d_in, const int* in_sizes, int n_in,
                              void* d_out, int out_size, void* d_ws, size_t ws_size,
                              hipStream_t stream) {
    const f4* x = (const f4*)d_in[0];            // (64, 100000, 3) fp32
    const float* W = (const float*)d_in[1];      // (40, 64) fp32
    const float* bias = (const float*)d_in[2];   // (40,) fp32
    float* out = (float*)d_out;                  // (64, 40) fp32

    // ws layout: pmin NBLK*3 f32 | pmax NBLK*3 f32 (fully rewritten per call)
    float* pmin = (float*)d_ws;
    float* pmax = pmin + NBLK * 3;

    minmax_k<<<NBLK, 256, 0, stream>>>(x, pmin, pmax, out);
    hist_gemv_k<<<NBLK, 256, 0, stream>>>(x, pmin, pmax, W, bias, out);
}

// Round 8
// 123.592 us; speedup vs baseline: 1.0367x; 1.0367x over previous
//
#include <hip/hip_runtime.h>

#define VR 4
#define NVOX 64            // VR^3
#define NCLS 40
#define NB 64
#define NPTS 100000
#define BPB 16             // blocks per batch
#define NBLK (NB * BPB)
#define G_PER_B (NPTS / 4)        // 25000 groups of 4 points (= 3 float4 each)
#define F4_PER_B (NPTS * 3 / 4)   // 75000 float4 per batch
#define STRIDE_G (BPB * 256)      // 4096 groups per step
#define FULL_ITERS (G_PER_B / STRIDE_G)            // 6 full (all-valid) iters
#define TAIL_G (G_PER_B - FULL_ITERS * STRIDE_G)   // 424 ragged groups
#define SW_LD 41                  // padded leading dim for transposed W in LDS
#define FLT_BIG 3.402823466e38f

typedef float f4 __attribute__((ext_vector_type(4)));

static __device__ __forceinline__ int bin1(float v, float mn, float s4) {
    int i = (int)((v - mn) * s4);   // v>=mn, s4>0 -> trunc==floor
    return i > (VR - 1) ? (VR - 1) : i;
}

// lane L of the wave owns voxel L: AND of per-bit (ballot XOR lane-complement)
static __device__ __forceinline__ unsigned long long vox_mask(
        int v, const unsigned long long* ns) {
    return (__ballot(v & 1)  ^ ns[0]) & (__ballot(v & 2)  ^ ns[1])
         & (__ballot(v & 4)  ^ ns[2]) & (__ballot(v & 8)  ^ ns[3])
         & (__ballot(v & 16) ^ ns[4]) & (__ballot(v & 32) ^ ns[5]);
}

// ---------------------------------------------------------------------------
// Block labeling (BOTH kernels): b = bid & 63, sub = bid >> 6. With
// round-robin bid->XCD (bid % 8), all 16 blocks of batch b sit on XCD b%8 in
// BOTH launches -> k2 re-reads k1's lines from the same L2 (+6.3 us, round 6).
// NOTE: nontemporal loads in k1 were tried (round 7) and REGRESSED +7 us:
// gfx950's nt flag evicts from L3 as well, so k2's re-read fell to HBM.
// Plain cached loads are correct here.
// ---------------------------------------------------------------------------

// ---------------------------------------------------------------------------
// Kernel 1: per-block per-dim min/max partials (pure ~77 MB HBM stream).
// sub==0 blocks also zero out[b] (ordered before k2 by the kernel boundary).
// ---------------------------------------------------------------------------
__global__ __launch_bounds__(256) void minmax_k(const f4* __restrict__ x,
                                                float* __restrict__ pmin,
                                                float* __restrict__ pmax,
                                                float* __restrict__ out) {
    const int bid = blockIdx.x;
    const int b = bid & (NB - 1);
    const int sub = bid >> 6;
    const f4* xb = x + (size_t)b * F4_PER_B;
    const int lane = threadIdx.x & 63;
    const int wv = threadIdx.x >> 6;
    const int t0 = sub * 256 + (int)threadIdx.x;

    if (sub == 0 && threadIdx.x < NCLS)   // zero the atomic accumulator
        out[b * NCLS + threadIdx.x] = 0.f;

    float mn0 = FLT_BIG, mn1 = FLT_BIG, mn2 = FLT_BIG;
    float mx0 = -FLT_BIG, mx1 = -FLT_BIG, mx2 = -FLT_BIG;
    #pragma unroll
    for (int k = 0; k < FULL_ITERS; k++) {         // no predication in hot loop
        const int g = t0 + k * STRIDE_G;
        const f4 a = xb[3 * g], c = xb[3 * g + 1], e = xb[3 * g + 2];
        // flat%3: a0->0 a1->1 a2->2 a3->0 c0->1 c1->2 c2->0 c3->1
        //         e0->2 e1->0 e2->1 e3->2
        mn0 = fminf(mn0, fminf(fminf(a[0], a[3]), fminf(c[2], e[1])));
        mx0 = fmaxf(mx0, fmaxf(fmaxf(a[0], a[3]), fmaxf(c[2], e[1])));
        mn1 = fminf(mn1, fminf(fminf(a[1], c[0]), fminf(c[3], e[2])));
        mx1 = fmaxf(mx1, fmaxf(fmaxf(a[1], c[0]), fmaxf(c[3], e[2])));
        mn2 = fminf(mn2, fminf(fminf(a[2], c[1]), fminf(e[0], e[3])));
        mx2 = fmaxf(mx2, fmaxf(fmaxf(a[2], c[1]), fmaxf(e[0], e[3])));
    }
    if (sub * 256 < TAIL_G && t0 < TAIL_G) {       // ragged tail: subs 0,1 only
        const int g = FULL_ITERS * STRIDE_G + t0;
        const f4 a = xb[3 * g], c = xb[3 * g + 1], e = xb[3 * g + 2];
        mn0 = fminf(mn0, fminf(fminf(a[0], a[3]), fminf(c[2], e[1])));
        mx0 = fmaxf(mx0, fmaxf(fmaxf(a[0], a[3]), fmaxf(c[2], e[1])));
        mn1 = fminf(mn1, fminf(fminf(a[1], c[0]), fminf(c[3], e[2])));
        mx1 = fmaxf(mx1, fmaxf(fmaxf(a[1], c[0]), fmaxf(c[3], e[2])));
        mn2 = fminf(mn2, fminf(fminf(a[2], c[1]), fminf(e[0], e[3])));
        mx2 = fmaxf(mx2, fmaxf(fmaxf(a[2], c[1]), fmaxf(e[0], e[3])));
    }

    #pragma unroll
    for (int off = 32; off > 0; off >>= 1) {
        mn0 = fminf(mn0, __shfl_down(mn0, off, 64));
        mn1 = fminf(mn1, __shfl_down(mn1, off, 64));
        mn2 = fminf(mn2, __shfl_down(mn2, off, 64));
        mx0 = fmaxf(mx0, __shfl_down(mx0, off, 64));
        mx1 = fmaxf(mx1, __shfl_down(mx1, off, 64));
        mx2 = fmaxf(mx2, __shfl_down(mx2, off, 64));
    }

    __shared__ float smn[4][3], smx[4][3];
    if (lane == 0) {
        smn[wv][0] = mn0; smn[wv][1] = mn1; smn[wv][2] = mn2;
        smx[wv][0] = mx0; smx[wv][1] = mx1; smx[wv][2] = mx2;
    }
    __syncthreads();
    if (threadIdx.x < 3) {
        const int d = threadIdx.x;
        float a = smn[0][d], z = smx[0][d];
        #pragma unroll
        for (int w = 1; w < 4; w++) {
            a = fminf(a, smn[w][d]);
            z = fmaxf(z, smx[w][d]);
        }
        pmin[(b * BPB + sub) * 3 + d] = a;
        pmax[(b * BPB + sub) * 3 + d] = z;
    }
}

// ---------------------------------------------------------------------------
// Kernel 2: ballot-count histogram + fused partial GEMV (atomicAdd to out).
// Re-reads x in REVERSE recency order (tail first, then k=5..0) on the SAME
// XCD as kernel 1 -> LRU-surviving L2 lines are consumed before eviction.
// Tail loads are issued into registers BEFORE sW staging / partial reduce so
// their latency hides under that work.
// ---------------------------------------------------------------------------
__global__ __launch_bounds__(256) void hist_gemv_k(const f4* __restrict__ x,
                                                   const float* __restrict__ pmin,
                                                   const float* __restrict__ pmax,
                                                   const float* __restrict__ W,
                                                   const float* __restrict__ bias,
                                                   float* __restrict__ out) {
    const int bid = blockIdx.x;
    const int b = bid & (NB - 1);
    const int sub = bid >> 6;
    const f4* xb = x + (size_t)b * F4_PER_B;
    const int lane = threadIdx.x & 63;
    const int wv = threadIdx.x >> 6;
    const int t0 = sub * 256 + (int)threadIdx.x;

    __shared__ float sW[NVOX * SW_LD];  // transposed [f][c], padded stride 41
    __shared__ float smm[6];            // mn0 mn1 mn2 mx0 mx1 mx2
    __shared__ unsigned swh[4][NVOX];
    __shared__ float fh[NVOX];

    // ---- tail prefetch (subs 0,1 only): issue before staging/reduce ----
    const bool hasTail = (sub * 256 < TAIL_G);
    const bool tailValid = hasTail && (t0 < TAIL_G);
    f4 ta = {0,0,0,0}, tc = {0,0,0,0}, te = {0,0,0,0};
    if (hasTail) {
        const int g = FULL_ITERS * STRIDE_G + (tailValid ? t0 : 0);
        ta = xb[3 * g]; tc = xb[3 * g + 1]; te = xb[3 * g + 2];
    }

    // ---- overlap with the tail-load latency ----
    for (int i = threadIdx.x; i < NCLS * NVOX; i += 256)
        sW[(i % NVOX) * SW_LD + (i / NVOX)] = W[i];
    if (threadIdx.x < 6) {              // reduce the 16 min/max partials
        const int d = threadIdx.x % 3;
        const bool isMax = threadIdx.x >= 3;
        float r = isMax ? -FLT_BIG : FLT_BIG;
        for (int s = 0; s < BPB; s++) {
            float v = isMax ? pmax[(b * BPB + s) * 3 + d]
                            : pmin[(b * BPB + s) * 3 + d];
            r = isMax ? fmaxf(r, v) : fminf(r, v);
        }
        smm[threadIdx.x] = r;
    }
    __syncthreads();
    const float bn0 = smm[0], bn1 = smm[1], bn2 = smm[2];
    const float s40 = (float)VR / (smm[3] - smm[0]);
    const float s41 = (float)VR / (smm[4] - smm[1]);
    const float s42 = (float)VR / (smm[5] - smm[2]);

    unsigned long long ns[6];
    #pragma unroll
    for (int k = 0; k < 6; k++)
        ns[k] = ((lane >> k) & 1) ? 0ull : ~0ull;

    unsigned cnt = 0;
    if (hasTail) {                      // tail first (k1 read it last -> L2)
        const unsigned long long vm = __ballot(tailValid);
        int v0 = bin1(ta[0], bn0, s40) * 16 + bin1(ta[1], bn1, s41) * 4 + bin1(ta[2], bn2, s42);
        int v1 = bin1(ta[3], bn0, s40) * 16 + bin1(tc[0], bn1, s41) * 4 + bin1(tc[1], bn2, s42);
        int v2 = bin1(tc[2], bn0, s40) * 16 + bin1(tc[3], bn1, s41) * 4 + bin1(te[0], bn2, s42);
        int v3 = bin1(te[1], bn0, s40) * 16 + bin1(te[2], bn1, s41) * 4 + bin1(te[3], bn2, s42);
        cnt += (unsigned)__popcll(vm & vox_mask(v0, ns));
        cnt += (unsigned)__popcll(vm & vox_mask(v1, ns));
        cnt += (unsigned)__popcll(vm & vox_mask(v2, ns));
        cnt += (unsigned)__popcll(vm & vox_mask(v3, ns));
    }
    #pragma unroll 2
    for (int k = FULL_ITERS - 1; k >= 0; k--) {    // reverse: recency order
        const int g = t0 + k * STRIDE_G;
        const f4 a = xb[3 * g], c = xb[3 * g + 1], e = xb[3 * g + 2];
        int v0 = bin1(a[0], bn0, s40) * 16 + bin1(a[1], bn1, s41) * 4 + bin1(a[2], bn2, s42);
        int v1 = bin1(a[3], bn0, s40) * 16 + bin1(c[0], bn1, s41) * 4 + bin1(c[1], bn2, s42);
        int v2 = bin1(c[2], bn0, s40) * 16 + bin1(c[3], bn1, s41) * 4 + bin1(e[0], bn2, s42);
        int v3 = bin1(e[1], bn0, s40) * 16 + bin1(e[2], bn1, s41) * 4 + bin1(e[3], bn2, s42);
        cnt += (unsigned)__popcll(vox_mask(v0, ns));
        cnt += (unsigned)__popcll(vox_mask(v1, ns));
        cnt += (unsigned)__popcll(vox_mask(v2, ns));
        cnt += (unsigned)__popcll(vox_mask(v3, ns));
    }

    swh[wv][lane] = cnt;
    __syncthreads();
    if (threadIdx.x < NVOX)
        fh[threadIdx.x] = (float)(swh[0][threadIdx.x] + swh[1][threadIdx.x] +
                                  swh[2][threadIdx.x] + swh[3][threadIdx.x])
                          * (1.0f / (float)NPTS);
    __syncthreads();
    if (threadIdx.x < NCLS) {                      // partial GEMV + atomic sum
        const int c = threadIdx.x;
        float acc = (sub == 0) ? bias[c] : 0.f;
        #pragma unroll
        for (int f = 0; f < NVOX; f++)
            acc += fh[f] * sW[f * SW_LD + c];      // padded: conflict-free
        atomicAdd(&out[b * NCLS + c], acc);
    }
}

extern "C" void kernel_launch(void* const* d_in, const int* in_sizes, int n_in,
                              void* d_out, int out_size, void* d_ws, size_t ws_size,
                              hipStream_t stream) {
    const f4* x = (const f4*)d_in[0];            // (64, 100000, 3) fp32
    const float* W = (const float*)d_in[1];      // (40, 64) fp32
    const float* bias = (const float*)d_in[2];   // (40,) fp32
    float* out = (float*)d_out;                  // (64, 40) fp32

    // ws layout: pmin NBLK*3 f32 | pmax NBLK*3 f32 (fully rewritten per call)
    float* pmin = (float*)d_ws;
    float* pmax = pmin + NBLK * 3;

    minmax_k<<<NBLK, 256, 0, stream>>>(x, pmin, pmax, out);
    hist_gemv_k<<<NBLK, 256, 0, stream>>>(x, pmin, pmax, W, bias, out);
}